// Round 4
// baseline (80.870 us; speedup 1.0000x reference)
//
#include <hip/hip_runtime.h>
#include <math.h>

#define NG 2048
#define IMG_W 128
#define IMG_H 128
#define L2E 1.4426950408889634f

typedef unsigned long long u64;

__device__ __forceinline__ float rlf(float x, int i) {
    return __int_as_float(__builtin_amdgcn_readlane(__float_as_int(x), i));
}

// Full per-gaussian preprocessing (verified math from rounds 0-3).
// COLORS=false skips the 4 sigmoid/color loads (phase-A cull only needs
// geometry). r2 = cull radius^2 (THR=24 log2-units, 1.05x slack); r2 = -1
// encodes invalid (z<=0.2 or det<=0) -> fails every cull test.
struct PrepOut {
    float u, v, A, B, C, al, cr, cg, cb, z, r2;
};

template <bool COLORS>
__device__ __forceinline__ PrepOut prep_g(
    int g,
    const float* __restrict__ mean, const float* __restrict__ qvec,
    const float* __restrict__ svec_raw, const float* __restrict__ color_raw,
    const float* __restrict__ alpha_raw,
    float fx, float fy, float cx, float cy,
    float R00, float R01, float R02, float t0,
    float R10, float R11, float R12, float t1,
    float R20, float R21, float R22, float t2)
{
    PrepOut o;
    float mx = mean[g * 3 + 0], my = mean[g * 3 + 1], mz = mean[g * 3 + 2];
    float x = R00 * mx + R01 * my + R02 * mz + t0;
    float y = R10 * mx + R11 * my + R12 * mz + t1;
    float z = R20 * mx + R21 * my + R22 * mz + t2;
    float zc = fmaxf(z, 0.001f);

    float qw = qvec[g * 4 + 0], qx = qvec[g * 4 + 1];
    float qy = qvec[g * 4 + 2], qz = qvec[g * 4 + 3];
    float qn = rsqrtf(qw * qw + qx * qx + qy * qy + qz * qz);
    qw *= qn; qx *= qn; qy *= qn; qz *= qn;
    float Rq00 = 1.f - 2.f * (qy * qy + qz * qz), Rq01 = 2.f * (qx * qy - qw * qz), Rq02 = 2.f * (qx * qz + qw * qy);
    float Rq10 = 2.f * (qx * qy + qw * qz), Rq11 = 1.f - 2.f * (qx * qx + qz * qz), Rq12 = 2.f * (qy * qz - qw * qx);
    float Rq20 = 2.f * (qx * qz - qw * qy), Rq21 = 2.f * (qy * qz + qw * qx), Rq22 = 1.f - 2.f * (qx * qx + qy * qy);

    float s0 = expf(svec_raw[g * 3 + 0]);
    float s1 = expf(svec_raw[g * 3 + 1]);
    float s2 = expf(svec_raw[g * 3 + 2]);
    float M00 = Rq00 * s0, M01 = Rq01 * s1, M02 = Rq02 * s2;
    float M10 = Rq10 * s0, M11 = Rq11 * s1, M12 = Rq12 * s2;
    float M20 = Rq20 * s0, M21 = Rq21 * s1, M22 = Rq22 * s2;

    float iz = 1.0f / zc;
    float J00 = fx * iz, J02 = -fx * x * iz * iz;
    float J11 = fy * iz, J12 = -fy * y * iz * iz;
    float T00 = J00 * R00 + J02 * R20;
    float T01 = J00 * R01 + J02 * R21;
    float T02 = J00 * R02 + J02 * R22;
    float T10 = J11 * R10 + J12 * R20;
    float T11 = J11 * R11 + J12 * R21;
    float T12 = J11 * R12 + J12 * R22;
    float TM00 = T00 * M00 + T01 * M10 + T02 * M20;
    float TM01 = T00 * M01 + T01 * M11 + T02 * M21;
    float TM02 = T00 * M02 + T01 * M12 + T02 * M22;
    float TM10 = T10 * M00 + T11 * M10 + T12 * M20;
    float TM11 = T10 * M01 + T11 * M11 + T12 * M21;
    float TM12 = T10 * M02 + T11 * M12 + T12 * M22;
    float a = TM00 * TM00 + TM01 * TM01 + TM02 * TM02 + 0.3f;
    float b = TM00 * TM10 + TM01 * TM11 + TM02 * TM12;
    float c = TM10 * TM10 + TM11 * TM11 + TM12 * TM12 + 0.3f;
    float det = a * c - b * b;
    float det_safe = fmaxf(det, 1e-8f);
    float inv_det = 1.0f / det_safe;
    bool valid = (z > 0.2f) && (det > 0.0f);

    float conic_a = c * inv_det;
    float conic_b = -b * inv_det;
    float conic_c = a * inv_det;

    float half_tr = 0.5f * (conic_a + conic_c);
    float half_df = 0.5f * (conic_a - conic_c);
    float lam_min = half_tr - sqrtf(half_df * half_df + conic_b * conic_b);
    float r2 = (lam_min > 1e-20f) ? (1.05f * 2.0f * 24.0f / (L2E * lam_min)) : 3.0e38f;
    if (!valid) r2 = -1.0f;

    o.u = fx * x * iz + cx;
    o.v = fy * y * iz + cy;
    o.A = -0.5f * L2E * conic_a;
    o.B = -L2E * conic_b;
    o.C = -0.5f * L2E * conic_c;
    o.z = z;
    o.r2 = r2;
    if (COLORS) {
        o.al = 1.0f / (1.0f + expf(-alpha_raw[g]));
        o.cr = 1.0f / (1.0f + expf(-color_raw[g * 3 + 0]));
        o.cg = 1.0f / (1.0f + expf(-color_raw[g * 3 + 1]));
        o.cb = 1.0f / (1.0f + expf(-color_raw[g * 3 + 2]));
    } else {
        o.al = o.cr = o.cg = o.cb = 0.f;
    }
    return o;
}

// Rank-count sort of K packed keys (unique: (z_bits<<16)|idx) across 256
// threads. NO = owned slots per thread (compile-time, uniform tier branch).
// Uniform m-loop reads pairs via ds_read_b128 broadcast; zkey[K] is padded
// with ~0 so an odd-K tail pair compares false. Scatters the 11-bit gaussian
// id to ssid[rank].
template <int NO>
__device__ __forceinline__ void sort_ranks(const u64* zkey,
                                           unsigned short* ssid,
                                           int K, int t)
{
    u64 myk[NO];
    int myr[NO];
#pragma unroll
    for (int o = 0; o < NO; ++o) {
        int j = t + 256 * o;
        myk[o] = (j < K) ? zkey[j] : ~0ull;
        myr[o] = 0;
    }
    const ulonglong2* z2 = (const ulonglong2*)zkey;
    const int np = (K + 1) >> 1;
    for (int i = 0; i < np; ++i) {
        ulonglong2 kk = z2[i];
#pragma unroll
        for (int o = 0; o < NO; ++o) {
            myr[o] += (kk.x < myk[o]) ? 1 : 0;
            myr[o] += (kk.y < myk[o]) ? 1 : 0;
        }
    }
#pragma unroll
    for (int o = 0; o < NO; ++o) {
        int j = t + 256 * o;
        if (j < K) ssid[myr[o]] = (unsigned short)(myk[o] & 0xFFFFu);
    }
}

// ---------------------------------------------------------------------------
// Single fused kernel. Grid (16,16) = 256 blocks = 1 block/CU; block = 256
// threads = 4 waves; one block renders one 8x8 pixel tile.
//   Phase A: 8 gaussians/thread full-prep-lite + cull vs tile; LDS-atomic
//            compaction of (z_bits,idx) keys. Kept subset's order under the
//            global stable z-sort == local sort by the same key.
//   Phase B: rank-count sort (above).
//   Phase C: 4 waves walk quarters of the sorted kept list (front-to-back);
//            lane j recomputes the full record for sorted entry base+j (f32
//            colors), ballot -> ctz readlane-walk (round-3 verified), per-
//            wave T<1e-6 early-out (residual contribution < 1e-6 << tol).
//   Merge:   in-order 4-segment merge through LDS (round-3 verified).
// No workspace, no global intermediates, no fences.
// ---------------------------------------------------------------------------
__global__ __launch_bounds__(256) void splat_kernel(
    const float* __restrict__ mean, const float* __restrict__ qvec,
    const float* __restrict__ svec_raw, const float* __restrict__ color_raw,
    const float* __restrict__ alpha_raw, const float* __restrict__ bg,
    const float* __restrict__ viewmat, const float* __restrict__ intrins,
    float* __restrict__ out)
{
    __shared__ __align__(16) u64 zkey[NG + 2];
    __shared__ unsigned short ssid[NG];
    __shared__ float4 part[4][64];
    __shared__ int scnt;

    const int t = threadIdx.x;
    const int wave = t >> 6;
    const int lane = t & 63;
    const int tx = blockIdx.x, ty = blockIdx.y;

    if (t == 0) scnt = 0;

    const float fx = intrins[0], fy = intrins[1], cx = intrins[2], cy = intrins[3];
    const float R00 = viewmat[0], R01 = viewmat[1], R02 = viewmat[2],  t0 = viewmat[3];
    const float R10 = viewmat[4], R11 = viewmat[5], R12 = viewmat[6],  t1 = viewmat[7];
    const float R20 = viewmat[8], R21 = viewmat[9], R22 = viewmat[10], t2 = viewmat[11];

    // tile pixel-center bounds
    const float x0 = tx * 8 + 0.5f, x1 = x0 + 7.0f;
    const float y0 = ty * 8 + 0.5f, y1 = y0 + 7.0f;

    __syncthreads(); // scnt = 0 visible

    // ---- phase A: prep-lite + cull + compaction ----
    for (int k = 0; k < 8; ++k) {
        int g = k * 256 + t;
        PrepOut p = prep_g<false>(g, mean, qvec, svec_raw, color_raw,
                                  alpha_raw, fx, fy, cx, cy,
                                  R00, R01, R02, t0, R10, R11, R12, t1,
                                  R20, R21, R22, t2);
        float dxm = fmaxf(0.f, fmaxf(x0 - p.u, p.u - x1));
        float dym = fmaxf(0.f, fmaxf(y0 - p.v, p.v - y1));
        if (dxm * dxm + dym * dym <= p.r2) {
            int slot = atomicAdd(&scnt, 1);
            zkey[slot] = ((u64)__float_as_uint(p.z) << 16) | (unsigned)g;
        }
    }
    __syncthreads();
    const int K = scnt;
    if (t == 0) zkey[K] = ~0ull; // pad for odd-K pair read
    __syncthreads();

    // ---- phase B: rank-count sort, tiered ownership (uniform branch) ----
    {
        const int nt = (K + 255) >> 8;
        if (nt <= 1)      sort_ranks<1>(zkey, ssid, K, t);
        else if (nt == 2) sort_ranks<2>(zkey, ssid, K, t);
        else if (nt == 3) sort_ranks<3>(zkey, ssid, K, t);
        else if (nt == 4) sort_ranks<4>(zkey, ssid, K, t);
        else              sort_ranks<8>(zkey, ssid, K, t);
    }
    __syncthreads();

    // ---- phase C: 4-wave segmented walk of the sorted kept list ----
    const float fpx = tx * 8 + (lane & 7) + 0.5f;
    const float fpy = ty * 8 + (lane >> 3) + 0.5f;
    float T = 1.f, Cr = 0.f, Cg = 0.f, Cb = 0.f;

    const int Kq = (K + 3) >> 2;
    const int s0 = wave * Kq;
    const int s1 = min(K, s0 + Kq);

    for (int base = s0; base < s1; base += 64) {
        const int j = base + lane;
        const bool inr = (j < s1);
        const int idx = inr ? (int)ssid[j] : 0;
        PrepOut p = prep_g<true>(idx, mean, qvec, svec_raw, color_raw,
                                 alpha_raw, fx, fy, cx, cy,
                                 R00, R01, R02, t0, R10, R11, R12, t1,
                                 R20, R21, R22, t2);
        u64 mask = __ballot(inr);
        while (mask) {
            const int i = (int)__builtin_ctzll(mask);
            mask &= mask - 1;
            float gu = rlf(p.u, i), gv_ = rlf(p.v, i);
            float gA = rlf(p.A, i), gB = rlf(p.B, i), gC = rlf(p.C, i);
            float al = rlf(p.al, i);
            float cr = rlf(p.cr, i), cg = rlf(p.cg, i), cb = rlf(p.cb, i);

            float dx = fpx - gu;
            float dy = fpy - gv_;
            float adx2 = gA * dx * dx;
            float bdx = gB * dx;
            float pw = fminf(fmaf(dy, fmaf(gC, dy, bdx), adx2), 0.f);
            float gv = exp2f(pw);
            float a = fminf(0.99f, al * gv);
            float w = a * T;
            Cr = fmaf(w, cr, Cr); Cg = fmaf(w, cg, Cg); Cb = fmaf(w, cb, Cb);
            T = fmaf(-a, T, T);
        }
        if (__all(T < 1e-6f)) break; // residual contribution < 1e-6
    }

    part[wave][lane] = make_float4(Cr, Cg, Cb, T);
    __syncthreads();

    if (wave == 0) {
        float4 p0 = part[0][lane];
        float4 p1 = part[1][lane];
        float4 p2 = part[2][lane];
        float4 p3 = part[3][lane];
        // in-order merge: C = C0 + T0*C1 + T0*T1*C2 + T0*T1*T2*C3
        float t01 = p0.w * p1.w;
        float t012 = t01 * p2.w;
        float R = p0.x + p0.w * p1.x + t01 * p2.x + t012 * p3.x;
        float G = p0.y + p0.w * p1.y + t01 * p2.y + t012 * p3.y;
        float Bc = p0.z + p0.w * p1.z + t01 * p2.z + t012 * p3.z;
        float Tt = t012 * p3.w;
        const int col = tx * 8 + (lane & 7);
        const int row = ty * 8 + (lane >> 3);
        const int pix = row * IMG_W + col;
        out[pix * 3 + 0] = R + Tt * bg[0];
        out[pix * 3 + 1] = G + Tt * bg[1];
        out[pix * 3 + 2] = Bc + Tt * bg[2];
    }
}

extern "C" void kernel_launch(void* const* d_in, const int* in_sizes, int n_in,
                              void* d_out, int out_size, void* d_ws, size_t ws_size,
                              hipStream_t stream)
{
    const float* mean      = (const float*)d_in[0];
    const float* qvec      = (const float*)d_in[1];
    const float* svec_raw  = (const float*)d_in[2];
    const float* color_raw = (const float*)d_in[3];
    const float* alpha_raw = (const float*)d_in[4];
    const float* bg        = (const float*)d_in[5];
    const float* viewmat   = (const float*)d_in[6];
    const float* intrins   = (const float*)d_in[7];
    float* out = (float*)d_out;
    (void)d_ws; (void)ws_size;

    hipLaunchKernelGGL(splat_kernel, dim3(16, 16), dim3(256), 0, stream,
                       mean, qvec, svec_raw, color_raw, alpha_raw, bg,
                       viewmat, intrins, out);
}

// Round 5
// 78.667 us; speedup vs baseline: 1.0280x; 1.0280x over previous
//
#include <hip/hip_runtime.h>
#include <math.h>

#define NG 2048
#define IMG_W 128
#define IMG_H 128
#define L2E 1.4426950408889634f
#define BLK 1024
#define NWAVE 16

typedef unsigned long long u64;

__device__ __forceinline__ float rlf(float x, int i) {
    return __int_as_float(__builtin_amdgcn_readlane(__float_as_int(x), i));
}

// Full per-gaussian preprocessing (verified math from rounds 0-4).
// COLORS=false skips the 4 sigmoid/color loads (phase-A cull only needs
// geometry). r2 = cull radius^2 (THR=24 log2-units, 1.05x slack); r2 = -1
// encodes invalid (z<=0.2 or det<=0) -> fails every cull test.
struct PrepOut {
    float u, v, A, B, C, al, cr, cg, cb, z, r2;
};

template <bool COLORS>
__device__ __forceinline__ PrepOut prep_g(
    int g,
    const float* __restrict__ mean, const float* __restrict__ qvec,
    const float* __restrict__ svec_raw, const float* __restrict__ color_raw,
    const float* __restrict__ alpha_raw,
    float fx, float fy, float cx, float cy,
    float R00, float R01, float R02, float t0,
    float R10, float R11, float R12, float t1,
    float R20, float R21, float R22, float t2)
{
    PrepOut o;
    float mx = mean[g * 3 + 0], my = mean[g * 3 + 1], mz = mean[g * 3 + 2];
    float x = R00 * mx + R01 * my + R02 * mz + t0;
    float y = R10 * mx + R11 * my + R12 * mz + t1;
    float z = R20 * mx + R21 * my + R22 * mz + t2;
    float zc = fmaxf(z, 0.001f);

    float qw = qvec[g * 4 + 0], qx = qvec[g * 4 + 1];
    float qy = qvec[g * 4 + 2], qz = qvec[g * 4 + 3];
    float qn = rsqrtf(qw * qw + qx * qx + qy * qy + qz * qz);
    qw *= qn; qx *= qn; qy *= qn; qz *= qn;
    float Rq00 = 1.f - 2.f * (qy * qy + qz * qz), Rq01 = 2.f * (qx * qy - qw * qz), Rq02 = 2.f * (qx * qz + qw * qy);
    float Rq10 = 2.f * (qx * qy + qw * qz), Rq11 = 1.f - 2.f * (qx * qx + qz * qz), Rq12 = 2.f * (qy * qz - qw * qx);
    float Rq20 = 2.f * (qx * qz - qw * qy), Rq21 = 2.f * (qy * qz + qw * qx), Rq22 = 1.f - 2.f * (qx * qx + qy * qy);

    float s0 = expf(svec_raw[g * 3 + 0]);
    float s1 = expf(svec_raw[g * 3 + 1]);
    float s2 = expf(svec_raw[g * 3 + 2]);
    float M00 = Rq00 * s0, M01 = Rq01 * s1, M02 = Rq02 * s2;
    float M10 = Rq10 * s0, M11 = Rq11 * s1, M12 = Rq12 * s2;
    float M20 = Rq20 * s0, M21 = Rq21 * s1, M22 = Rq22 * s2;

    float iz = 1.0f / zc;
    float J00 = fx * iz, J02 = -fx * x * iz * iz;
    float J11 = fy * iz, J12 = -fy * y * iz * iz;
    float T00 = J00 * R00 + J02 * R20;
    float T01 = J00 * R01 + J02 * R21;
    float T02 = J00 * R02 + J02 * R22;
    float T10 = J11 * R10 + J12 * R20;
    float T11 = J11 * R11 + J12 * R21;
    float T12 = J11 * R12 + J12 * R22;
    float TM00 = T00 * M00 + T01 * M10 + T02 * M20;
    float TM01 = T00 * M01 + T01 * M11 + T02 * M21;
    float TM02 = T00 * M02 + T01 * M12 + T02 * M22;
    float TM10 = T10 * M00 + T11 * M10 + T12 * M20;
    float TM11 = T10 * M01 + T11 * M11 + T12 * M21;
    float TM12 = T10 * M02 + T11 * M12 + T12 * M22;
    float a = TM00 * TM00 + TM01 * TM01 + TM02 * TM02 + 0.3f;
    float b = TM00 * TM10 + TM01 * TM11 + TM02 * TM12;
    float c = TM10 * TM10 + TM11 * TM11 + TM12 * TM12 + 0.3f;
    float det = a * c - b * b;
    float det_safe = fmaxf(det, 1e-8f);
    float inv_det = 1.0f / det_safe;
    bool valid = (z > 0.2f) && (det > 0.0f);

    float conic_a = c * inv_det;
    float conic_b = -b * inv_det;
    float conic_c = a * inv_det;

    float half_tr = 0.5f * (conic_a + conic_c);
    float half_df = 0.5f * (conic_a - conic_c);
    float lam_min = half_tr - sqrtf(half_df * half_df + conic_b * conic_b);
    float r2 = (lam_min > 1e-20f) ? (1.05f * 2.0f * 24.0f / (L2E * lam_min)) : 3.0e38f;
    if (!valid) r2 = -1.0f;

    o.u = fx * x * iz + cx;
    o.v = fy * y * iz + cy;
    o.A = -0.5f * L2E * conic_a;
    o.B = -L2E * conic_b;
    o.C = -0.5f * L2E * conic_c;
    o.z = z;
    o.r2 = r2;
    if (COLORS) {
        o.al = 1.0f / (1.0f + expf(-alpha_raw[g]));
        o.cr = 1.0f / (1.0f + expf(-color_raw[g * 3 + 0]));
        o.cg = 1.0f / (1.0f + expf(-color_raw[g * 3 + 1]));
        o.cb = 1.0f / (1.0f + expf(-color_raw[g * 3 + 2]));
    } else {
        o.al = o.cr = o.cg = o.cb = 0.f;
    }
    return o;
}

// Rank-count sort of K packed keys (unique: (z_bits<<16)|idx) across BLK
// threads. NO = owned slots per thread (compile-time, uniform tier branch;
// with BLK=1024 only 1 or 2). Uniform m-loop reads key pairs via
// ds_read_b128 broadcast; zkey[K] is padded with ~0 so an odd-K tail pair
// compares false. Scatters the 11-bit gaussian id to ssid[rank]; ranks are
// unique (keys unique) so no write conflicts.
template <int NO>
__device__ __forceinline__ void sort_ranks(const u64* zkey,
                                           unsigned short* ssid,
                                           int K, int t)
{
    u64 myk[NO];
    int myr[NO];
#pragma unroll
    for (int o = 0; o < NO; ++o) {
        int j = t + BLK * o;
        myk[o] = (j < K) ? zkey[j] : ~0ull;
        myr[o] = 0;
    }
    const ulonglong2* z2 = (const ulonglong2*)zkey;
    const int np = (K + 1) >> 1;
    for (int i = 0; i < np; ++i) {
        ulonglong2 kk = z2[i];
#pragma unroll
        for (int o = 0; o < NO; ++o) {
            myr[o] += (kk.x < myk[o]) ? 1 : 0;
            myr[o] += (kk.y < myk[o]) ? 1 : 0;
        }
    }
#pragma unroll
    for (int o = 0; o < NO; ++o) {
        int j = t + BLK * o;
        if (j < K) ssid[myr[o]] = (unsigned short)(myk[o] & 0xFFFFu);
    }
}

// ---------------------------------------------------------------------------
// Single fused kernel. Grid (16,16) = 256 blocks, block = 1024 threads =
// 16 waves (4 waves/SIMD at 1 block/CU -> real latency hiding, the round-4
// fix). One block renders one 8x8 pixel tile.
//   Phase A: 2 gaussians/thread full-prep-lite + cull vs tile; LDS-atomic
//            compaction of (z_bits,idx) keys. Kept subset's order under the
//            global stable z-sort == local sort by the same key.
//   Phase B: rank-count sort (above), <=2 owned keys/thread.
//   Phase C: 16 waves walk sixteenths of the sorted kept list (front-to-
//            back); lane j recomputes the full record for its sorted entry
//            (f32 colors), ballot -> ctz readlane-walk (round-3 verified),
//            per-wave T<1e-6 early-out (residual contribution < 1e-6).
//   Merge:   in-order 16-segment merge through LDS by wave 0.
// No workspace, no global intermediates, no fences.
// ---------------------------------------------------------------------------
__global__ __launch_bounds__(BLK) void splat_kernel(
    const float* __restrict__ mean, const float* __restrict__ qvec,
    const float* __restrict__ svec_raw, const float* __restrict__ color_raw,
    const float* __restrict__ alpha_raw, const float* __restrict__ bg,
    const float* __restrict__ viewmat, const float* __restrict__ intrins,
    float* __restrict__ out)
{
    __shared__ __align__(16) u64 zkey[NG + 2];
    __shared__ unsigned short ssid[NG];
    __shared__ float4 part[NWAVE][64];
    __shared__ int scnt;

    const int t = threadIdx.x;
    const int wave = t >> 6;
    const int lane = t & 63;
    const int tx = blockIdx.x, ty = blockIdx.y;

    if (t == 0) scnt = 0;

    const float fx = intrins[0], fy = intrins[1], cx = intrins[2], cy = intrins[3];
    const float R00 = viewmat[0], R01 = viewmat[1], R02 = viewmat[2],  t0 = viewmat[3];
    const float R10 = viewmat[4], R11 = viewmat[5], R12 = viewmat[6],  t1 = viewmat[7];
    const float R20 = viewmat[8], R21 = viewmat[9], R22 = viewmat[10], t2 = viewmat[11];

    // tile pixel-center bounds
    const float x0 = tx * 8 + 0.5f, x1 = x0 + 7.0f;
    const float y0 = ty * 8 + 0.5f, y1 = y0 + 7.0f;

    __syncthreads(); // scnt = 0 visible

    // ---- phase A: prep-lite + cull + compaction (2 gaussians/thread) ----
#pragma unroll
    for (int k = 0; k < NG / BLK; ++k) {
        int g = k * BLK + t;
        PrepOut p = prep_g<false>(g, mean, qvec, svec_raw, color_raw,
                                  alpha_raw, fx, fy, cx, cy,
                                  R00, R01, R02, t0, R10, R11, R12, t1,
                                  R20, R21, R22, t2);
        float dxm = fmaxf(0.f, fmaxf(x0 - p.u, p.u - x1));
        float dym = fmaxf(0.f, fmaxf(y0 - p.v, p.v - y1));
        if (dxm * dxm + dym * dym <= p.r2) {
            int slot = atomicAdd(&scnt, 1);
            zkey[slot] = ((u64)__float_as_uint(p.z) << 16) | (unsigned)g;
        }
    }
    __syncthreads();
    const int K = scnt;
    if (t == 0) zkey[K] = ~0ull; // pad for odd-K pair read
    __syncthreads();

    // ---- phase B: rank-count sort (uniform tier branch, NO in {1,2}) ----
    if (K <= BLK) sort_ranks<1>(zkey, ssid, K, t);
    else          sort_ranks<2>(zkey, ssid, K, t);
    __syncthreads();

    // ---- phase C: 16-wave segmented walk of the sorted kept list ----
    const float fpx = tx * 8 + (lane & 7) + 0.5f;
    const float fpy = ty * 8 + (lane >> 3) + 0.5f;
    float T = 1.f, Cr = 0.f, Cg = 0.f, Cb = 0.f;

    const int Kq = (K + NWAVE - 1) / NWAVE;
    const int s0 = wave * Kq;
    const int s1 = min(K, s0 + Kq);

    for (int base = s0; base < s1; base += 64) {
        const int j = base + lane;
        const bool inr = (j < s1);
        const int idx = inr ? (int)ssid[j] : 0;
        PrepOut p = prep_g<true>(idx, mean, qvec, svec_raw, color_raw,
                                 alpha_raw, fx, fy, cx, cy,
                                 R00, R01, R02, t0, R10, R11, R12, t1,
                                 R20, R21, R22, t2);
        u64 mask = __ballot(inr);
        while (mask) {
            const int i = (int)__builtin_ctzll(mask);
            mask &= mask - 1;
            float gu = rlf(p.u, i), gv_ = rlf(p.v, i);
            float gA = rlf(p.A, i), gB = rlf(p.B, i), gC = rlf(p.C, i);
            float al = rlf(p.al, i);
            float cr = rlf(p.cr, i), cg = rlf(p.cg, i), cb = rlf(p.cb, i);

            float dx = fpx - gu;
            float dy = fpy - gv_;
            float adx2 = gA * dx * dx;
            float bdx = gB * dx;
            float pw = fminf(fmaf(dy, fmaf(gC, dy, bdx), adx2), 0.f);
            float gv = exp2f(pw);
            float a = fminf(0.99f, al * gv);
            float w = a * T;
            Cr = fmaf(w, cr, Cr); Cg = fmaf(w, cg, Cg); Cb = fmaf(w, cb, Cb);
            T = fmaf(-a, T, T);
        }
        if (__all(T < 1e-6f)) break; // residual contribution < 1e-6
    }

    part[wave][lane] = make_float4(Cr, Cg, Cb, T);
    __syncthreads();

    // ---- in-order 16-segment merge (wave 0) ----
    if (wave == 0) {
        float4 acc = part[0][lane];
#pragma unroll
        for (int s = 1; s < NWAVE; ++s) {
            float4 p = part[s][lane];
            acc.x = fmaf(acc.w, p.x, acc.x);
            acc.y = fmaf(acc.w, p.y, acc.y);
            acc.z = fmaf(acc.w, p.z, acc.z);
            acc.w *= p.w;
        }
        const int col = tx * 8 + (lane & 7);
        const int row = ty * 8 + (lane >> 3);
        const int pix = row * IMG_W + col;
        out[pix * 3 + 0] = acc.x + acc.w * bg[0];
        out[pix * 3 + 1] = acc.y + acc.w * bg[1];
        out[pix * 3 + 2] = acc.z + acc.w * bg[2];
    }
}

extern "C" void kernel_launch(void* const* d_in, const int* in_sizes, int n_in,
                              void* d_out, int out_size, void* d_ws, size_t ws_size,
                              hipStream_t stream)
{
    const float* mean      = (const float*)d_in[0];
    const float* qvec      = (const float*)d_in[1];
    const float* svec_raw  = (const float*)d_in[2];
    const float* color_raw = (const float*)d_in[3];
    const float* alpha_raw = (const float*)d_in[4];
    const float* bg        = (const float*)d_in[5];
    const float* viewmat   = (const float*)d_in[6];
    const float* intrins   = (const float*)d_in[7];
    float* out = (float*)d_out;
    (void)d_ws; (void)ws_size;

    hipLaunchKernelGGL(splat_kernel, dim3(16, 16), dim3(BLK), 0, stream,
                       mean, qvec, svec_raw, color_raw, alpha_raw, bg,
                       viewmat, intrins, out);
}

// Round 6
// 74.585 us; speedup vs baseline: 1.0843x; 1.0547x over previous
//
#include <hip/hip_runtime.h>
#include <math.h>

#define NG 2048
#define IMG_W 128
#define IMG_H 128
#define L2E 1.4426950408889634f
#define THR 18.0f
#define BLK 1024
#define NWAVE 16

typedef unsigned long long u64;

__device__ __forceinline__ float rlf(float x, int i) {
    return __int_as_float(__builtin_amdgcn_readlane(__float_as_int(x), i));
}

// Raw-hardware transcendentals (~1 ulp; all inputs verified in-range:
// exp2 args in [-40, 15], rcp args > 1e-8, rsq args ~1, sqrt args >= 0).
__device__ __forceinline__ float fexp2(float x) { return __builtin_amdgcn_exp2f(x); }
__device__ __forceinline__ float frcp(float x)  { return __builtin_amdgcn_rcpf(x); }
__device__ __forceinline__ float frsq(float x)  { return __builtin_amdgcn_rsqf(x); }
__device__ __forceinline__ float fsqr(float x)  { return __builtin_amdgcn_sqrtf(x); }
__device__ __forceinline__ float fexp(float x)  { return fexp2(x * L2E); }
__device__ __forceinline__ float fsig(float x)  { return frcp(1.f + fexp2(-x * L2E)); }

// Full per-gaussian preprocessing (verified math from rounds 0-5).
// COLORS=false skips the 4 sigmoid/color loads (phase-A cull only needs
// geometry). r2 = cull radius^2 (THR log2-units, 1.05x slack); r2 = -1
// encodes invalid (z<=0.2 or det<=0) -> fails every cull test.
struct PrepOut {
    float u, v, A, B, C, al, cr, cg, cb, z, r2;
};

template <bool COLORS>
__device__ __forceinline__ PrepOut prep_g(
    int g,
    const float* __restrict__ mean, const float* __restrict__ qvec,
    const float* __restrict__ svec_raw, const float* __restrict__ color_raw,
    const float* __restrict__ alpha_raw,
    float fx, float fy, float cx, float cy,
    float R00, float R01, float R02, float t0,
    float R10, float R11, float R12, float t1,
    float R20, float R21, float R22, float t2)
{
    PrepOut o;
    float mx = mean[g * 3 + 0], my = mean[g * 3 + 1], mz = mean[g * 3 + 2];
    float x = R00 * mx + R01 * my + R02 * mz + t0;
    float y = R10 * mx + R11 * my + R12 * mz + t1;
    float z = R20 * mx + R21 * my + R22 * mz + t2;
    float zc = fmaxf(z, 0.001f);

    float qw = qvec[g * 4 + 0], qx = qvec[g * 4 + 1];
    float qy = qvec[g * 4 + 2], qz = qvec[g * 4 + 3];
    float qn = frsq(qw * qw + qx * qx + qy * qy + qz * qz);
    qw *= qn; qx *= qn; qy *= qn; qz *= qn;
    float Rq00 = 1.f - 2.f * (qy * qy + qz * qz), Rq01 = 2.f * (qx * qy - qw * qz), Rq02 = 2.f * (qx * qz + qw * qy);
    float Rq10 = 2.f * (qx * qy + qw * qz), Rq11 = 1.f - 2.f * (qx * qx + qz * qz), Rq12 = 2.f * (qy * qz - qw * qx);
    float Rq20 = 2.f * (qx * qz - qw * qy), Rq21 = 2.f * (qy * qz + qw * qx), Rq22 = 1.f - 2.f * (qx * qx + qy * qy);

    float s0 = fexp(svec_raw[g * 3 + 0]);
    float s1 = fexp(svec_raw[g * 3 + 1]);
    float s2 = fexp(svec_raw[g * 3 + 2]);
    float M00 = Rq00 * s0, M01 = Rq01 * s1, M02 = Rq02 * s2;
    float M10 = Rq10 * s0, M11 = Rq11 * s1, M12 = Rq12 * s2;
    float M20 = Rq20 * s0, M21 = Rq21 * s1, M22 = Rq22 * s2;

    float iz = frcp(zc);
    float J00 = fx * iz, J02 = -fx * x * iz * iz;
    float J11 = fy * iz, J12 = -fy * y * iz * iz;
    float T00 = J00 * R00 + J02 * R20;
    float T01 = J00 * R01 + J02 * R21;
    float T02 = J00 * R02 + J02 * R22;
    float T10 = J11 * R10 + J12 * R20;
    float T11 = J11 * R11 + J12 * R21;
    float T12 = J11 * R12 + J12 * R22;
    float TM00 = T00 * M00 + T01 * M10 + T02 * M20;
    float TM01 = T00 * M01 + T01 * M11 + T02 * M21;
    float TM02 = T00 * M02 + T01 * M12 + T02 * M22;
    float TM10 = T10 * M00 + T11 * M10 + T12 * M20;
    float TM11 = T10 * M01 + T11 * M11 + T12 * M21;
    float TM12 = T10 * M02 + T11 * M12 + T12 * M22;
    float a = TM00 * TM00 + TM01 * TM01 + TM02 * TM02 + 0.3f;
    float b = TM00 * TM10 + TM01 * TM11 + TM02 * TM12;
    float c = TM10 * TM10 + TM11 * TM11 + TM12 * TM12 + 0.3f;
    float det = a * c - b * b;
    float det_safe = fmaxf(det, 1e-8f);
    float inv_det = frcp(det_safe);
    bool valid = (z > 0.2f) && (det > 0.0f);

    float conic_a = c * inv_det;
    float conic_b = -b * inv_det;
    float conic_c = a * inv_det;

    float half_tr = 0.5f * (conic_a + conic_c);
    float half_df = 0.5f * (conic_a - conic_c);
    float lam_min = half_tr - fsqr(half_df * half_df + conic_b * conic_b);
    float r2 = (lam_min > 1e-20f) ? (1.05f * 2.0f * THR / (L2E * lam_min)) : 3.0e38f;
    if (!valid) r2 = -1.0f;

    o.u = fx * x * iz + cx;
    o.v = fy * y * iz + cy;
    o.A = -0.5f * L2E * conic_a;
    o.B = -L2E * conic_b;
    o.C = -0.5f * L2E * conic_c;
    o.z = z;
    o.r2 = r2;
    if (COLORS) {
        o.al = fsig(alpha_raw[g]);
        o.cr = fsig(color_raw[g * 3 + 0]);
        o.cg = fsig(color_raw[g * 3 + 1]);
        o.cb = fsig(color_raw[g * 3 + 2]);
    } else {
        o.al = o.cr = o.cg = o.cb = 0.f;
    }
    return o;
}

// Rank-count sort of K packed keys (unique: (z_bits<<16)|idx) across BLK
// threads. NO = owned slots per thread (compile-time, uniform tier branch;
// with BLK=1024 only 1 or 2). Uniform m-loop reads key pairs via
// ds_read_b128 broadcast; zkey[K] is padded with ~0 so an odd-K tail pair
// compares false. Scatters the 11-bit gaussian id to ssid[rank]; ranks are
// unique (keys unique) so no write conflicts. Contains no barriers, so
// wave-uniform callers may skip it entirely (round-6 gating).
template <int NO>
__device__ __forceinline__ void sort_ranks(const u64* zkey,
                                           unsigned short* ssid,
                                           int K, int t)
{
    u64 myk[NO];
    int myr[NO];
#pragma unroll
    for (int o = 0; o < NO; ++o) {
        int j = t + BLK * o;
        myk[o] = (j < K) ? zkey[j] : ~0ull;
        myr[o] = 0;
    }
    const ulonglong2* z2 = (const ulonglong2*)zkey;
    const int np = (K + 1) >> 1;
    for (int i = 0; i < np; ++i) {
        ulonglong2 kk = z2[i];
#pragma unroll
        for (int o = 0; o < NO; ++o) {
            myr[o] += (kk.x < myk[o]) ? 1 : 0;
            myr[o] += (kk.y < myk[o]) ? 1 : 0;
        }
    }
#pragma unroll
    for (int o = 0; o < NO; ++o) {
        int j = t + BLK * o;
        if (j < K) ssid[myr[o]] = (unsigned short)(myk[o] & 0xFFFFu);
    }
}

// ---------------------------------------------------------------------------
// Single fused kernel. Grid (16,16) = 256 blocks, block = 1024 threads =
// 16 waves (4 waves/SIMD at 1 block/CU). One block renders one 8x8 tile.
//   Phase A: 2 gaussians/thread full-prep-lite + cull vs tile; LDS-atomic
//            compaction of (z_bits,idx) keys. Kept subset's order under the
//            global stable z-sort == local sort by the same key.
//   Phase B: rank-count sort, gated to waves that own live keys (round-6:
//            idle waves skip straight to the barrier -> frees issue slots).
//   Phase C: 16 waves walk sixteenths of the sorted kept list (front-to-
//            back); lane j recomputes the full record for its sorted entry
//            (f32 colors), ballot -> ctz readlane-walk (round-3 verified),
//            per-wave T<1e-6 early-out (residual contribution < 1e-6).
//   Merge:   in-order 16-segment merge through LDS by wave 0.
// No workspace, no global intermediates, no fences.
// ---------------------------------------------------------------------------
__global__ __launch_bounds__(BLK) void splat_kernel(
    const float* __restrict__ mean, const float* __restrict__ qvec,
    const float* __restrict__ svec_raw, const float* __restrict__ color_raw,
    const float* __restrict__ alpha_raw, const float* __restrict__ bg,
    const float* __restrict__ viewmat, const float* __restrict__ intrins,
    float* __restrict__ out)
{
    __shared__ __align__(16) u64 zkey[NG + 2];
    __shared__ unsigned short ssid[NG];
    __shared__ float4 part[NWAVE][64];
    __shared__ int scnt;

    const int t = threadIdx.x;
    const int wave = t >> 6;
    const int lane = t & 63;
    const int tx = blockIdx.x, ty = blockIdx.y;

    if (t == 0) scnt = 0;

    const float fx = intrins[0], fy = intrins[1], cx = intrins[2], cy = intrins[3];
    const float R00 = viewmat[0], R01 = viewmat[1], R02 = viewmat[2],  t0 = viewmat[3];
    const float R10 = viewmat[4], R11 = viewmat[5], R12 = viewmat[6],  t1 = viewmat[7];
    const float R20 = viewmat[8], R21 = viewmat[9], R22 = viewmat[10], t2 = viewmat[11];

    // tile pixel-center bounds
    const float x0 = tx * 8 + 0.5f, x1 = x0 + 7.0f;
    const float y0 = ty * 8 + 0.5f, y1 = y0 + 7.0f;

    __syncthreads(); // scnt = 0 visible

    // ---- phase A: prep-lite + cull + compaction (2 gaussians/thread) ----
#pragma unroll
    for (int k = 0; k < NG / BLK; ++k) {
        int g = k * BLK + t;
        PrepOut p = prep_g<false>(g, mean, qvec, svec_raw, color_raw,
                                  alpha_raw, fx, fy, cx, cy,
                                  R00, R01, R02, t0, R10, R11, R12, t1,
                                  R20, R21, R22, t2);
        float dxm = fmaxf(0.f, fmaxf(x0 - p.u, p.u - x1));
        float dym = fmaxf(0.f, fmaxf(y0 - p.v, p.v - y1));
        if (dxm * dxm + dym * dym <= p.r2) {
            int slot = atomicAdd(&scnt, 1);
            zkey[slot] = ((u64)__float_as_uint(p.z) << 16) | (unsigned)g;
        }
    }
    __syncthreads();
    const int K = scnt;
    if (t == 0) zkey[K] = ~0ull; // pad for odd-K pair read
    __syncthreads();

    // ---- phase B: rank-count sort, gated to active waves ----
    if (K > BLK) {
        sort_ranks<2>(zkey, ssid, K, t);   // K > 1024: every wave owns keys
    } else if ((t & ~63) < K) {            // wave-uniform activity test
        sort_ranks<1>(zkey, ssid, K, t);
    }
    __syncthreads();

    // ---- phase C: 16-wave segmented walk of the sorted kept list ----
    const float fpx = tx * 8 + (lane & 7) + 0.5f;
    const float fpy = ty * 8 + (lane >> 3) + 0.5f;
    float T = 1.f, Cr = 0.f, Cg = 0.f, Cb = 0.f;

    const int Kq = (K + NWAVE - 1) / NWAVE;
    const int s0 = wave * Kq;
    const int s1 = min(K, s0 + Kq);

    for (int base = s0; base < s1; base += 64) {
        const int j = base + lane;
        const bool inr = (j < s1);
        const int idx = inr ? (int)ssid[j] : 0;
        PrepOut p = prep_g<true>(idx, mean, qvec, svec_raw, color_raw,
                                 alpha_raw, fx, fy, cx, cy,
                                 R00, R01, R02, t0, R10, R11, R12, t1,
                                 R20, R21, R22, t2);
        u64 mask = __ballot(inr);
        while (mask) {
            const int i = (int)__builtin_ctzll(mask);
            mask &= mask - 1;
            float gu = rlf(p.u, i), gv_ = rlf(p.v, i);
            float gA = rlf(p.A, i), gB = rlf(p.B, i), gC = rlf(p.C, i);
            float al = rlf(p.al, i);
            float cr = rlf(p.cr, i), cg = rlf(p.cg, i), cb = rlf(p.cb, i);

            float dx = fpx - gu;
            float dy = fpy - gv_;
            float adx2 = gA * dx * dx;
            float bdx = gB * dx;
            float pw = fminf(fmaf(dy, fmaf(gC, dy, bdx), adx2), 0.f);
            float gv = fexp2(pw);
            float a = fminf(0.99f, al * gv);
            float w = a * T;
            Cr = fmaf(w, cr, Cr); Cg = fmaf(w, cg, Cg); Cb = fmaf(w, cb, Cb);
            T = fmaf(-a, T, T);
        }
        if (__all(T < 1e-6f)) break; // residual contribution < 1e-6
    }

    part[wave][lane] = make_float4(Cr, Cg, Cb, T);
    __syncthreads();

    // ---- in-order 16-segment merge (wave 0) ----
    if (wave == 0) {
        float4 acc = part[0][lane];
#pragma unroll
        for (int s = 1; s < NWAVE; ++s) {
            float4 p = part[s][lane];
            acc.x = fmaf(acc.w, p.x, acc.x);
            acc.y = fmaf(acc.w, p.y, acc.y);
            acc.z = fmaf(acc.w, p.z, acc.z);
            acc.w *= p.w;
        }
        const int col = tx * 8 + (lane & 7);
        const int row = ty * 8 + (lane >> 3);
        const int pix = row * IMG_W + col;
        out[pix * 3 + 0] = acc.x + acc.w * bg[0];
        out[pix * 3 + 1] = acc.y + acc.w * bg[1];
        out[pix * 3 + 2] = acc.z + acc.w * bg[2];
    }
}

extern "C" void kernel_launch(void* const* d_in, const int* in_sizes, int n_in,
                              void* d_out, int out_size, void* d_ws, size_t ws_size,
                              hipStream_t stream)
{
    const float* mean      = (const float*)d_in[0];
    const float* qvec      = (const float*)d_in[1];
    const float* svec_raw  = (const float*)d_in[2];
    const float* color_raw = (const float*)d_in[3];
    const float* alpha_raw = (const float*)d_in[4];
    const float* bg        = (const float*)d_in[5];
    const float* viewmat   = (const float*)d_in[6];
    const float* intrins   = (const float*)d_in[7];
    float* out = (float*)d_out;
    (void)d_ws; (void)ws_size;

    hipLaunchKernelGGL(splat_kernel, dim3(16, 16), dim3(BLK), 0, stream,
                       mean, qvec, svec_raw, color_raw, alpha_raw, bg,
                       viewmat, intrins, out);
}